// Round 12
// baseline (204.617 us; speedup 1.0000x reference)
//
#include <hip/hip_runtime.h>
#include <hip/hip_bf16.h>
#include <math.h>

typedef __bf16 bf16;
typedef __bf16 bf16x8 __attribute__((ext_vector_type(8)));
typedef unsigned short ushort8 __attribute__((ext_vector_type(8)));
typedef float floatx4 __attribute__((ext_vector_type(4)));

#define MFMA_BF16(a, b, c) __builtin_amdgcn_mfma_f32_16x16x32_bf16(a, b, c, 0, 0, 0)

// Q pre-scale: (1/sqrt(64)) * log2(e)  -> scores in log2 domain, p = exp2(s)
#define Q_SCALE 0.18033688011112042f
#define NEG_INVFREQ_LOG2 0.41524101186092029f  // log2(10000)/32
#define INV_2PI 0.15915494309189535f

#if __has_builtin(__builtin_amdgcn_exp2f)
#define EXP2F(x) __builtin_amdgcn_exp2f(x)
#else
#define EXP2F(x) exp2f(x)
#endif

__device__ __forceinline__ void hw_sincos_rev(float rev, float* sn, float* cs) {
#if __has_builtin(__builtin_amdgcn_sinf) && __has_builtin(__builtin_amdgcn_cosf) && \
    __has_builtin(__builtin_amdgcn_fractf)
  const float f = __builtin_amdgcn_fractf(rev);
  *sn = __builtin_amdgcn_sinf(f);
  *cs = __builtin_amdgcn_cosf(f);
#else
  sincosf(rev * 6.2831853071795864f, sn, cs);
#endif
}

__device__ __forceinline__ bf16x8 cvt8(const float4 a, const float4 b) {
  bf16x8 t;
  t[0] = (bf16)a.x; t[1] = (bf16)a.y; t[2] = (bf16)a.z; t[3] = (bf16)a.w;
  t[4] = (bf16)b.x; t[5] = (bf16)b.y; t[6] = (bf16)b.z; t[7] = (bf16)b.w;
  return t;
}

__device__ __forceinline__ unsigned int pack2(float a, float b) {
#if __has_builtin(__builtin_amdgcn_cvt_pk_bf16_f32)
  return __builtin_bit_cast(unsigned int, __builtin_amdgcn_cvt_pk_bf16_f32(a, b));
#else
  unsigned short lo = __builtin_bit_cast(unsigned short, (bf16)a);
  unsigned short hi = __builtin_bit_cast(unsigned short, (bf16)b);
  return (unsigned int)lo | ((unsigned int)hi << 16);
#endif
}

// async global->LDS, 16B/lane; LDS dest = wave-uniform base + lane*16B.
__device__ __forceinline__ void gld16(const bf16* g, bf16* l) {
  __builtin_amdgcn_global_load_lds(
      (const __attribute__((address_space(1))) unsigned int*)g,
      (__attribute__((address_space(3))) unsigned int*)l, 16, 0, 0);
}

// ---------------------------------------------------------------------------
// Fused prep: cast x -> bf16 (blocks 0..2047), transpose-cast W_qkv
// (blocks 2048..3583, tiles 48x32), transpose-cast W_out (3584..4095, 16x32).
// ---------------------------------------------------------------------------
__device__ __forceinline__ void transpose_tile(const float* __restrict__ in,
                                               bf16* __restrict__ out, int N,
                                               int bx, int by, int t,
                                               bf16 (*T)[40]) {
  const int k0 = by * 32, n0 = bx * 64;
  {
    const int k = t >> 3, n8 = (t & 7) * 8;
    const float* p = &in[(size_t)(k0 + k) * N + n0 + n8];
    const float4 a = *(const float4*)p;
    const float4 b = *(const float4*)(p + 4);
    const float v[8] = {a.x, a.y, a.z, a.w, b.x, b.y, b.z, b.w};
#pragma unroll
    for (int j = 0; j < 8; j++) {
      const int n = n8 + j;
      T[n][k ^ (8 * ((n >> 3) & 3))] = (bf16)v[j];
    }
  }
  __syncthreads();
  {
    const int n = t >> 2, k8 = (t & 3) * 8;
    const int kp = k8 ^ (8 * ((n >> 3) & 3));
    *(bf16x8*)&out[(size_t)(n0 + n) * 1024 + k0 + k8] = *(const bf16x8*)&T[n][kp];
  }
}

__global__ __launch_bounds__(256) void prep_kernel(
    const float* __restrict__ x, bf16* __restrict__ xb,
    const float* __restrict__ Wq, bf16* __restrict__ Wqt,
    const float* __restrict__ Wo, bf16* __restrict__ Wot) {
  __shared__ __align__(16) bf16 T[64][40];
  const int bid = blockIdx.x, t = threadIdx.x;
  if (bid < 2048) {
    const int i = bid * 256 + t;
    const float4 a = *(const float4*)&x[(size_t)i * 8];
    const float4 b = *(const float4*)&x[(size_t)i * 8 + 4];
    *(bf16x8*)&xb[(size_t)i * 8] = cvt8(a, b);
  } else if (bid < 3584) {
    const int bb = bid - 2048;
    transpose_tile(Wq, Wqt, 3072, bb % 48, bb / 48, t, T);
  } else {
    const int bb = bid - 3584;
    transpose_tile(Wo, Wot, 1024, bb % 16, bb / 16, t, T);
  }
}

// ---------------------------------------------------------------------------
// GEMM: C[M,N] = A[M,K](bf16) @ Bt[N,K](bf16)^T + bias.
// Tile 128 x TN, BK=64, 256 thr. Split-half LDS [2][rows][32].
// MODE 0: fp32 out. MODE 1 (TN=128): qkv scatter with fused RoPE on Q,K.
// ---------------------------------------------------------------------------
template <int TN, int MODE>
__global__ __launch_bounds__(256) void gemm_kernel(
    const bf16* __restrict__ A, const bf16* __restrict__ Bt,
    const float* __restrict__ bias, void* __restrict__ out0,
    bf16* __restrict__ outK, bf16* __restrict__ outV, int M, int N, int K) {
  constexpr int NI = TN / 32;
  constexpr int BI = TN / 32;
  __shared__ __align__(16) bf16 As2[2][128][32];
  __shared__ __align__(16) bf16 Bs2[2][TN][32];

  const int tid = threadIdx.x, lane = tid & 63, w = tid >> 6;
  const int c = lane & 15, quad = lane >> 4;
  const int wm = w >> 1, wn = w & 1;
  const int m0 = blockIdx.y * 128, n0 = blockIdx.x * TN;
  const int srow = lane >> 2, scol = (lane & 3) * 8;

  floatx4 acc[4][NI] = {};

  for (int k0 = 0; k0 < K; k0 += 64) {
    __syncthreads();
#pragma unroll
    for (int i = 0; i < 4; i++) {
      const int seg = w * 4 + i;
      const int kh = seg >> 3, r0 = (seg & 7) * 16;
      gld16(&A[(size_t)(m0 + r0 + srow) * K + k0 + kh * 32 + scol],
            &As2[kh][r0][0]);
    }
#pragma unroll
    for (int i = 0; i < BI; i++) {
      const int seg = w * BI + i;
      const int kh = seg / (TN / 16), r0 = (seg % (TN / 16)) * 16;
      gld16(&Bt[(size_t)(n0 + r0 + srow) * K + k0 + kh * 32 + scol],
            &Bs2[kh][r0][0]);
    }
    __syncthreads();

#pragma unroll
    for (int kh = 0; kh < 2; kh++) {
      bf16x8 af[4], bfr[NI];
#pragma unroll
      for (int mi = 0; mi < 4; mi++)
        af[mi] = *(const bf16x8*)&As2[kh][wm * 64 + mi * 16 + c][quad * 8];
#pragma unroll
      for (int ni = 0; ni < NI; ni++)
        bfr[ni] = *(const bf16x8*)&Bs2[kh][wn * (TN / 2) + ni * 16 + c][quad * 8];
#pragma unroll
      for (int mi = 0; mi < 4; mi++)
#pragma unroll
        for (int ni = 0; ni < NI; ni++)
          acc[mi][ni] = MFMA_BF16(af[mi], bfr[ni], acc[mi][ni]);
    }
  }

  if (MODE == 0) {
#pragma unroll
    for (int mi = 0; mi < 4; mi++)
#pragma unroll
      for (int ni = 0; ni < NI; ni++)
#pragma unroll
        for (int r = 0; r < 4; r++) {
          const int row = m0 + wm * 64 + mi * 16 + quad * 4 + r;
          const int col = n0 + wn * (TN / 2) + ni * 16 + c;
          ((float*)out0)[(size_t)row * N + col] = acc[mi][ni][r] + bias[col];
        }
  } else {
    const int colb = n0 + wn * (TN / 2);     // 64-aligned: one (t, head)
    const int t = colb >> 10;                // 0=Q 1=K 2=V
    const int h = (colb & 1023) >> 6;
    bf16* dst = (t == 0) ? (bf16*)out0 : (t == 1 ? outK : outV);
    if (t == 2) {
#pragma unroll
      for (int mi = 0; mi < 4; mi++)
#pragma unroll
        for (int ni = 0; ni < NI; ni++)
#pragma unroll
          for (int r = 0; r < 4; r++) {
            const int row = m0 + wm * 64 + mi * 16 + quad * 4 + r;
            const int col = colb + ni * 16 + c;
            const int b = row >> 11, s = row & 2047;
            dst[(((size_t)b * 16 + h) * 2048 + s) * 64 + (col & 63)] =
                (bf16)(acc[mi][ni][r] + bias[col]);
          }
    } else {
      const float qs = (t == 0) ? Q_SCALE : 1.0f;
      const float invr[2] = {exp2f(-NEG_INVFREQ_LOG2 * (float)c) * INV_2PI,
                             exp2f(-NEG_INVFREQ_LOG2 * (float)(16 + c)) * INV_2PI};
#pragma unroll
      for (int mi = 0; mi < 4; mi++) {
#pragma unroll
        for (int r = 0; r < 4; r++) {
          const int row = m0 + wm * 64 + mi * 16 + quad * 4 + r;
          const int b = row >> 11, s = row & 2047;
          const size_t base = (((size_t)b * 16 + h) * 2048 + s) * 64;
#pragma unroll
          for (int ni = 0; ni < 2; ni++) {
            float sn, cs;
            hw_sincos_rev((float)s * invr[ni], &sn, &cs);
            const float v1 = acc[mi][ni][r] + bias[colb + ni * 16 + c];
            const float v2 = acc[mi][ni + 2][r] + bias[colb + (ni + 2) * 16 + c];
            const int d = ni * 16 + c;
            dst[base + d] = (bf16)((v1 * cs - v2 * sn) * qs);
            dst[base + d + 32] = (bf16)((v2 * cs + v1 * sn) * qs);
          }
        }
      }
    }
  }
}

// ---------------------------------------------------------------------------
// Causal attention, split-K x2. Block (p, j, bh) handles q-tiles p and 31-p,
// k-tiles kt = j, j+2, ... (<= qtile). (o,l) accumulate linearly (no running
// max; scores in log2 domain -> p = exp2(s)). fp32 partials to Opart/Lpart,
// merged by merge_kernel. 1024 blocks -> 4/CU -> 16 waves of TLP.
// ---------------------------------------------------------------------------
struct AttnState {
  floatx4 o[4];
  float l;
};

__device__ __forceinline__ void attn_step(
    const bf16x8 qf[2], const bf16x8 kf[4][2], const bf16x8 vf[4][2],
    bf16 (*PsW)[72], AttnState& st, int qglob, int kbase, bool diag, int c,
    int quad) {
  floatx4 sacc[4] = {};
#pragma unroll
  for (int kg = 0; kg < 4; kg++)
#pragma unroll
    for (int dh = 0; dh < 2; dh++)
      sacc[kg] = MFMA_BF16(kf[kg][dh], qf[dh], sacc[kg]);

#pragma unroll
  for (int kg = 0; kg < 4; kg++) {
    float p[4];
#pragma unroll
    for (int r = 0; r < 4; r++) {
      float e = EXP2F(sacc[kg][r]);
      if (diag && (kbase + kg * 16 + quad * 4 + r > qglob)) e = 0.0f;
      p[r] = e;
    }
    st.l += (p[0] + p[1]) + (p[2] + p[3]);
    const uint2 u = {pack2(p[0], p[1]), pack2(p[2], p[3])};
    *(uint2*)&PsW[c][kg * 16 + quad * 4] = u;
  }

  bf16x8 pf[2];
#pragma unroll
  for (int ks = 0; ks < 2; ks++)
    pf[ks] = *(const bf16x8*)&PsW[c][ks * 32 + quad * 8];

#pragma unroll
  for (int dg = 0; dg < 4; dg++)
#pragma unroll
    for (int ks = 0; ks < 2; ks++)
      st.o[dg] = MFMA_BF16(vf[dg][ks], pf[ks], st.o[dg]);
}

__global__ __launch_bounds__(256) void attn_part_kernel(
    const bf16* __restrict__ Q, const bf16* __restrict__ K,
    const bf16* __restrict__ V, float* __restrict__ Opart,
    float* __restrict__ Lpart) {
  const int S = 2048;
  const int p = blockIdx.x;   // pair 0..15
  const int j = blockIdx.y;   // k-half 0..1
  const int bh = blockIdx.z;  // 0..31
  const int tid = threadIdx.x, lane = tid & 63, wave = tid >> 6;
  const int c = lane & 15, quad = lane >> 4;

  __shared__ __align__(16) bf16 Ks2[2][64][32];
  __shared__ __align__(16) bf16 Vt[64][72];
  __shared__ __align__(16) bf16 Ps[4][16][72];

  const bf16* Qb = Q + (size_t)bh * S * 64;
  const bf16* Kb = K + (size_t)bh * S * 64;
  const bf16* Vb = V + (size_t)bh * S * 64;

  const int qA = p, qB = 31 - p;
  const int qgA = qA * 64 + wave * 16 + c;
  const int qgB = qB * 64 + wave * 16 + c;

  bf16x8 qfA[2], qfB[2];
#pragma unroll
  for (int dh = 0; dh < 2; dh++) {
    qfA[dh] = *(const bf16x8*)&Qb[(size_t)qgA * 64 + dh * 32 + quad * 8];
    qfB[dh] = *(const bf16x8*)&Qb[(size_t)qgB * 64 + dh * 32 + quad * 8];
  }

  AttnState stA = {}, stB = {};

  const int vcc = (tid & 7) * 8;
  const int vr2 = ((tid >> 3) + 4 * (tid & 7)) & 31;
  const int ksr = lane >> 2, ksc = (lane & 3) * 8;

  for (int kt = j; kt <= qB; kt += 2) {
    __syncthreads();
#pragma unroll
    for (int i = 0; i < 2; i++) {
      const int seg = wave * 2 + i;
      const int dh = seg >> 2, r0 = (seg & 3) * 16;
      gld16(&Kb[(size_t)(kt * 64 + r0 + ksr) * 64 + dh * 32 + ksc],
            &Ks2[dh][r0][0]);
    }
    {
      const bf16* vs = &Vb[(size_t)(kt * 64 + 2 * vr2) * 64 + vcc];
      const ushort8 w0 = __builtin_bit_cast(ushort8, *(const bf16x8*)vs);
      const ushort8 w1 = __builtin_bit_cast(ushort8, *(const bf16x8*)(vs + 64));
#pragma unroll
      for (int jj = 0; jj < 8; jj++)
        *(unsigned int*)&Vt[vcc + jj][2 * vr2] =
            (unsigned int)w0[jj] | ((unsigned int)w1[jj] << 16);
    }
    __syncthreads();

    bf16x8 kf[4][2];
#pragma unroll
    for (int kg = 0; kg < 4; kg++)
#pragma unroll
      for (int dh = 0; dh < 2; dh++)
        kf[kg][dh] = *(const bf16x8*)&Ks2[dh][kg * 16 + c][quad * 8];

    bf16x8 vf[4][2];
#pragma unroll
    for (int dg = 0; dg < 4; dg++)
#pragma unroll
      for (int ks = 0; ks < 2; ks++)
        vf[dg][ks] = *(const bf16x8*)&Vt[dg * 16 + c][ks * 32 + quad * 8];

    attn_step(qfB, kf, vf, Ps[wave], stB, qgB, kt * 64, kt == qB, c, quad);
    if (kt <= qA)
      attn_step(qfA, kf, vf, Ps[wave], stA, qgA, kt * 64, kt == qA, c, quad);
  }

  // reduce l across quads (all lanes get full sum)
  stA.l += __shfl_xor(stA.l, 16);
  stA.l += __shfl_xor(stA.l, 32);
  stB.l += __shfl_xor(stB.l, 16);
  stB.l += __shfl_xor(stB.l, 32);

  float* Ob = Opart + ((size_t)j * 32 + bh) * S * 64;
  float* Lb = Lpart + ((size_t)j * 32 + bh) * S;
#pragma unroll
  for (int dg = 0; dg < 4; dg++) {
    *(floatx4*)&Ob[(size_t)qgA * 64 + dg * 16 + quad * 4] = stA.o[dg];
    *(floatx4*)&Ob[(size_t)qgB * 64 + dg * 16 + quad * 4] = stB.o[dg];
  }
  if (quad == 0) {
    Lb[qgA] = stA.l;
    Lb[qgB] = stB.l;
  }
}

// ---------------------------------------------------------------------------
// merge: AO[b][s][h*64+d] = (O0+O1)/(l0+l1), bf16. 4 elems/thread.
// ---------------------------------------------------------------------------
__global__ __launch_bounds__(256) void merge_kernel(
    const float* __restrict__ Opart, const float* __restrict__ Lpart,
    bf16* __restrict__ AO) {
  const int t = blockIdx.x * 256 + threadIdx.x;  // 0..2^20
  const int d4 = t & 15;
  const int q = (t >> 4) & 2047;
  const int bh = t >> 15;
  const size_t half = (size_t)32 * 2048 * 64;
  const size_t off = ((size_t)bh * 2048 + q) * 64 + d4 * 4;
  const float4 o0 = *(const float4*)&Opart[off];
  const float4 o1 = *(const float4*)&Opart[half + off];
  const float iv = 1.0f / (Lpart[bh * 2048 + q] + Lpart[32 * 2048 + bh * 2048 + q]);
  const int b = bh >> 4, h = bh & 15;
  const uint2 u = {pack2((o0.x + o1.x) * iv, (o0.y + o1.y) * iv),
                   pack2((o0.z + o1.z) * iv, (o0.w + o1.w) * iv)};
  *(uint2*)&AO[((size_t)(b * 2048 + q)) * 1024 + h * 64 + d4 * 4] = u;
}

// ---------------------------------------------------------------------------
extern "C" void kernel_launch(void* const* d_in, const int* in_sizes, int n_in,
                              void* d_out, int out_size, void* d_ws,
                              size_t ws_size, hipStream_t stream) {
  const float* x = (const float*)d_in[0];
  const float* W_qkv = (const float*)d_in[1];
  const float* b_qkv = (const float*)d_in[2];
  const float* W_out = (const float*)d_in[3];
  const float* b_out = (const float*)d_in[4];
  float* out = (float*)d_out;

  const size_t qn = (size_t)2 * 16 * 2048 * 64;  // 4,194,304

  // ws (74 MB): [xb 8 | AO alias][Wqkvt 6][Wot 2][Q 8][K 8][V 8]
  //             [Opart 33.5 fp32][Lpart 0.5 fp32]
  bf16* xb = (bf16*)d_ws;
  bf16* Wqkvt = xb + qn;
  bf16* Wot = Wqkvt + 3072 * 1024;
  bf16* Qw = Wot + 1024 * 1024;
  bf16* Kw = Qw + qn;
  bf16* Vw = Kw + qn;
  float* Opart = (float*)(Vw + qn);
  float* Lpart = Opart + 2 * (size_t)32 * 2048 * 64;
  bf16* AO = xb;  // alias: xb dead after gemm_qkv

  prep_kernel<<<dim3(4096), 256, 0, stream>>>(x, xb, W_qkv, Wqkvt, W_out, Wot);
  gemm_kernel<128, 1><<<dim3(3072 / 128, 4096 / 128), 256, 0, stream>>>(
      xb, Wqkvt, b_qkv, Qw, Kw, Vw, 4096, 3072, 1024);
  attn_part_kernel<<<dim3(16, 2, 32), 256, 0, stream>>>(Qw, Kw, Vw, Opart, Lpart);
  merge_kernel<<<dim3(4096), 256, 0, stream>>>(Opart, Lpart, AO);
  gemm_kernel<64, 0><<<dim3(1024 / 64, 4096 / 128), 256, 0, stream>>>(
      AO, Wot, b_out, out, nullptr, nullptr, 4096, 1024, 1024);
}